// Round 4
// baseline (335.418 us; speedup 1.0000x reference)
//
#include <hip/hip_runtime.h>

#define D_IN_   50937
#define D_LYR_  50425
#define NCH     24
#define NBE     16
#define NME     128
#define NOUT    168
#define NPAD    192
#define KROWS   50688        // padded GEMM K: 256 melody + 50432 lyrics (mult of 64)
#define KSPLIT  16
#define TOTSTEP 792          // KROWS/64
#define PARTN   (2048*168)   // 344064

typedef __attribute__((ext_vector_type(8))) short short8;
typedef __attribute__((ext_vector_type(4))) float f32x4;
typedef float f32x4u __attribute__((ext_vector_type(4), aligned(4)));
typedef __attribute__((ext_vector_type(2))) unsigned int u32x2;

static __device__ __forceinline__ unsigned short f2bf(float f) {
    unsigned int u = __float_as_uint(f);
    u += 0x7FFF + ((u >> 16) & 1);          // round-to-nearest-even
    return (unsigned short)(u >> 16);
}
static __device__ __forceinline__ unsigned int pack2(float x, float y) {
    return (unsigned int)f2bf(x) | ((unsigned int)f2bf(y) << 16);
}

// scalar W[d][n] over concatenated heads
static __device__ __forceinline__ float wsrc(const float* wc, const float* wb,
                                             const float* wm, int d, int n) {
    if (n < NCH)        return wc[d * NCH + n];
    if (n < NCH + NBE)  return wb[d * NBE + (n - NCH)];
    if (n < NOUT)       return wm[(long)d * NME + (n - NCH - NBE)];
    return 0.f;
}
// quad W[d][n0..n0+3]; head boundaries (24,40,168) are 4-aligned so quads never straddle
static __device__ __forceinline__ f32x4 wsrc4(const float* wc, const float* wb,
                                              const float* wm, int d, int nq) {
    int n0 = nq * 4;
    if (n0 < 24)  return *(const f32x4*)(wc + d * 24 + n0);
    if (n0 < 40)  return *(const f32x4*)(wb + d * 16 + (n0 - 24));
    if (n0 < 168) return *(const f32x4*)(wm + (long)d * 128 + (n0 - 40));
    f32x4 z = {0.f, 0.f, 0.f, 0.f};
    return z;
}

// folded, transposed, bf16 weights: wbt[n][r], r = d-256
__global__ __launch_bounds__(256) void k_fold(const float* wc, const float* wb,
                                              const float* wm_, const float* conv_w,
                                              unsigned short* wbt) {
    __shared__ unsigned short tile[64 * 196];   // [dloc][n], pad 196 (8B-aligned rows)
    float cw0 = conv_w[3], cw1 = conv_w[4], cw2 = conv_w[5];
    int r0 = blockIdx.x * 64;
    int tid = threadIdx.x;
    for (int i = 0; i < 12; ++i) {
        int idx = tid + i * 256;                // 64 rows x 48 quads
        int dl = idx / 48, nq = idx % 48;
        int r = r0 + dl;
        f32x4 v = {0.f, 0.f, 0.f, 0.f};
        if (r < 50681) {
            int d = 256 + r;
            f32x4 w0 = wsrc4(wc, wb, wm_, d, nq);
            f32x4 wn1 = wsrc4(wc, wb, wm_, d - 1, nq);
            v = cw1 * w0 + cw2 * wn1;
            if (d + 1 < D_IN_) v += cw0 * wsrc4(wc, wb, wm_, d + 1, nq);
        }
        u32x2 p; p.x = pack2(v.x, v.y); p.y = pack2(v.z, v.w);
        *(u32x2*)&tile[dl * 196 + nq * 4] = p;
    }
    __syncthreads();
    for (int i = 0; i < 6; ++i) {
        int idx = tid + i * 256;                // 192 n x 8 chunks
        int n = idx >> 3, ch = idx & 7;
        short8 o;
        for (int j = 0; j < 8; ++j) o[j] = (short)tile[(ch * 8 + j) * 196 + n];
        *(short8*)(wbt + (long)n * KROWS + r0 + ch * 8) = o;
    }
}

// C[j] = bias + ctx @ W'[0:256, j] (+ conv_b * colsum, generally zero); ctx fused in
__global__ void k_cvec(const int* genre, const int* tempo, const int* keysig,
                       const float* emb,
                       const float* wc, const float* wb, const float* wm_,
                       const float* conv_w, const float* conv_b,
                       const float* bc, const float* bb, const float* bm_, float* C) {
    int j = blockIdx.x;          // 0..167
    int lane = threadIdx.x;      // 64
    int g = genre[0], tt = tempo[0], kk = keysig[0];
    float cw0 = conv_w[3], cw1 = conv_w[4], cw2 = conv_w[5];
    float s = 0.f;
    for (int d = lane; d < 256; d += 64) {
        float cx = emb[g * 256 + d] + emb[(10 + tt) * 256 + d] +
                   emb[(20 + kk) * 256 + d] + emb[34 * 256 + d];
        float wp = cw1 * wsrc(wc, wb, wm_, d, j) + cw0 * wsrc(wc, wb, wm_, d + 1, j);
        if (d > 0) wp += cw2 * wsrc(wc, wb, wm_, d - 1, j);
        s += cx * wp;
    }
    float cb = conv_b[0];
    if (cb != 0.f) {
        float cs = 0.f;
        for (int d = lane; d < D_IN_; d += 64) cs += wsrc(wc, wb, wm_, d, j);
        s += cb * cs;
    }
    for (int off = 32; off; off >>= 1) s += __shfl_down(s, off);
    if (lane == 0) {
        float b = (j < NCH) ? bc[j] : (j < NCH + NBE) ? bb[j - NCH] : bm_[j - NCH - NBE];
        C[j] = s + b;
    }
}

// Split-K GEMM, NO LDS, NO BARRIERS: both operands straight to registers.
// Block = 256 thr (4 waves), tile 32 rows x 192 cols x ~3168 K.
// Waves = 4 N-groups (48 cols each); every wave covers all 32 rows (2 A-frags).
// A double-buffered in named registers (HBM latency); B issued just-in-time (L2-resident).
__global__ __launch_bounds__(256, 3) void k_gemm(const float* mel, const float* lyr,
                                                 const unsigned short* wbt,
                                                 float* partial) {
    const int blk = blockIdx.x;
    const int ks = ((blk & 7) << 1) | ((blk >> 3) & 1);  // same-ks blocks share an XCD L2
    const int bm = blk >> 4;                             // 0..63 (32-row tiles)
    const int tid = threadIdx.x, lane = tid & 63, wv = tid >> 6;
    const int l15 = lane & 15, lk = lane >> 4;
    const int start = ks * 49 + (ks < 8 ? ks : 8);
    const int cnt = 49 + (ks < 8 ? 1 : 0);

    // per-lane operand base pointers
    const float* melB[2];
    const float* lyrB[2];
    const unsigned short* bB[3];
    #pragma unroll
    for (int mi = 0; mi < 2; ++mi) {
        int row = bm * 32 + mi * 16 + l15;
        melB[mi] = mel + row * 256;
        lyrB[mi] = lyr + (long)row * D_LYR_ - 256;   // +r gives the right lyric col
    }
    #pragma unroll
    for (int ni = 0; ni < 3; ++ni) {
        int n = wv * 48 + ni * 16 + l15;
        bB[ni] = wbt + (long)n * KROWS;
    }

    f32x4 acc[2][3];
    #pragma unroll
    for (int mi = 0; mi < 2; ++mi)
        #pragma unroll
        for (int ni = 0; ni < 3; ++ni) acc[mi][ni] = (f32x4){0.f, 0.f, 0.f, 0.f};

    auto loadA = [&](int t, f32x4* dst) {           // dst[8]: [(mi*2+kk)*2 + half]
        int gt = start + t;
        int r0 = gt * 64;
        #pragma unroll
        for (int mi = 0; mi < 2; ++mi) {
            #pragma unroll
            for (int kk = 0; kk < 2; ++kk) {
                int r = r0 + kk * 32 + lk * 8;
                const float* p = (r < 256) ? (melB[mi] + r) : (lyrB[mi] + r);
                f32x4 v0, v1;
                if (gt != TOTSTEP - 1) {
                    v0 = *(const f32x4u*)p;
                    v1 = *(const f32x4u*)(p + 4);
                } else {                             // tail tile: zero-pad past D_LYR_
                    int c = r - 256;
                    #pragma unroll
                    for (int q = 0; q < 4; ++q) {
                        v0[q] = (c + q     < D_LYR_) ? p[q]     : 0.f;
                        v1[q] = (c + 4 + q < D_LYR_) ? p[4 + q] : 0.f;
                    }
                }
                dst[(mi * 2 + kk) * 2]     = v0;
                dst[(mi * 2 + kk) * 2 + 1] = v1;
            }
        }
    };

    auto loadB = [&](int t, short8* bf) {           // bf[6]: [ni*2+kk]
        int r0 = (start + t) * 64;
        #pragma unroll
        for (int ni = 0; ni < 3; ++ni)
            #pragma unroll
            for (int kk = 0; kk < 2; ++kk)
                bf[ni * 2 + kk] =
                    *(const short8*)(bB[ni] + r0 + kk * 32 + lk * 8);
    };

    auto compute = [&](const f32x4* a, const short8* bf) {
        short8 af[4];                                // [mi*2+kk]
        #pragma unroll
        for (int f = 0; f < 4; ++f) {
            f32x4 v0 = a[f * 2], v1 = a[f * 2 + 1];
            short8 o;
            o[0] = (short)f2bf(v0.x); o[1] = (short)f2bf(v0.y);
            o[2] = (short)f2bf(v0.z); o[3] = (short)f2bf(v0.w);
            o[4] = (short)f2bf(v1.x); o[5] = (short)f2bf(v1.y);
            o[6] = (short)f2bf(v1.z); o[7] = (short)f2bf(v1.w);
            af[f] = o;
        }
        #pragma unroll
        for (int kk = 0; kk < 2; ++kk)
            #pragma unroll
            for (int ni = 0; ni < 3; ++ni)
                #pragma unroll
                for (int mi = 0; mi < 2; ++mi)
                    acc[mi][ni] = __builtin_amdgcn_mfma_f32_16x16x32_bf16(
                        af[mi * 2 + kk], bf[ni * 2 + kk], acc[mi][ni], 0, 0, 0);
    };

    f32x4 aA[8], aB[8];
    short8 bf[6];
    loadA(0, aA);
    int t = 0;
    while (true) {
        loadB(t, bf);                         // in flight over the pack
        if (t + 1 < cnt) loadA(t + 1, aB);    // deep prefetch (HBM)
        compute(aA, bf);
        if (++t >= cnt) break;
        loadB(t, bf);
        if (t + 1 < cnt) loadA(t + 1, aA);
        compute(aB, bf);
        if (++t >= cnt) break;
    }

    // deterministic partial store
    float* pbase = partial + (long)ks * PARTN;
    #pragma unroll
    for (int mi = 0; mi < 2; ++mi) {
        int rb = bm * 32 + mi * 16 + lk * 4;
        #pragma unroll
        for (int ni = 0; ni < 3; ++ni) {
            int col = wv * 48 + ni * 16 + l15;
            if (col < NOUT) {
                #pragma unroll
                for (int q = 0; q < 4; ++q)
                    pbase[(long)(rb + q) * NOUT + col] = acc[mi][ni][q];
            }
        }
    }
}

__global__ void k_reduce(const float* partial, const float* C, float* out) {
    int idx = blockIdx.x * 256 + threadIdx.x;    // vec4 index
    if (idx >= PARTN / 4) return;
    int base = idx * 4;
    f32x4 s;
    for (int q = 0; q < 4; ++q) s[q] = C[(base + q) % NOUT];
    for (int ks = 0; ks < KSPLIT; ++ks)
        s += *(const f32x4*)(partial + (long)ks * PARTN + base);
    *(f32x4*)(out + base) = s;
}

extern "C" void kernel_launch(void* const* d_in, const int* in_sizes, int n_in,
                              void* d_out, int out_size, void* d_ws, size_t ws_size,
                              hipStream_t stream) {
    const int*   genre   = (const int*)d_in[0];
    const int*   tempo   = (const int*)d_in[1];
    const int*   keysig  = (const int*)d_in[2];
    const float* mel     = (const float*)d_in[4];
    const float* lyr     = (const float*)d_in[5];
    const float* emb     = (const float*)d_in[6];
    const float* conv_w  = (const float*)d_in[7];
    const float* conv_b  = (const float*)d_in[8];
    const float* w_chord = (const float*)d_in[9];
    const float* b_chord = (const float*)d_in[10];
    const float* w_beat  = (const float*)d_in[11];
    const float* b_beat  = (const float*)d_in[12];
    const float* w_mel   = (const float*)d_in[13];
    const float* b_mel   = (const float*)d_in[14];

    char* ws = (char*)d_ws;
    unsigned short* wbt = (unsigned short*)ws;              // 192*50688*2 = 19,464,192 B
    float* Cvec    = (float*)(ws + 19464192);               // 1 KB
    float* partial = (float*)(ws + 19466240);               // 16*344064*4 = 22,020,096 B
    float* out     = (float*)d_out;

    hipLaunchKernelGGL(k_fold, dim3(TOTSTEP), dim3(256), 0, stream,
                       w_chord, w_beat, w_mel, conv_w, wbt);
    hipLaunchKernelGGL(k_cvec, dim3(NOUT), dim3(64), 0, stream,
                       genre, tempo, keysig, emb,
                       w_chord, w_beat, w_mel, conv_w, conv_b,
                       b_chord, b_beat, b_mel, Cvec);
    hipLaunchKernelGGL(k_gemm, dim3(1024), dim3(256), 0, stream,
                       mel, lyr, wbt, partial);
    hipLaunchKernelGGL(k_reduce, dim3((PARTN / 4 + 255) / 256), dim3(256), 0, stream,
                       partial, Cvec, out);
}

// Round 6
// 224.484 us; speedup vs baseline: 1.4942x; 1.4942x over previous
//
#include <hip/hip_runtime.h>

#define D_IN_   50937
#define D_LYR_  50425
#define NCH     24
#define NBE     16
#define NME     128
#define NOUT    168
#define NPAD    192
#define KROWS   50688        // padded GEMM K: 256 melody + 50432 lyrics (mult of 64)
#define KSPLIT  16
#define TOTSTEP 792          // KROWS/64
#define PARTN   (2048*168)   // 344064

typedef __attribute__((ext_vector_type(8))) short short8;
typedef __attribute__((ext_vector_type(4))) float f32x4;
typedef float f32x4u __attribute__((ext_vector_type(4), aligned(4)));
typedef __attribute__((ext_vector_type(2))) unsigned int u32x2;
typedef __attribute__((address_space(3))) unsigned int lds_u32;
typedef const __attribute__((address_space(1))) unsigned int glob_u32;

static __device__ __forceinline__ unsigned short f2bf(float f) {
    unsigned int u = __float_as_uint(f);
    u += 0x7FFF + ((u >> 16) & 1);          // round-to-nearest-even
    return (unsigned short)(u >> 16);
}
static __device__ __forceinline__ unsigned int pack2(float x, float y) {
    return (unsigned int)f2bf(x) | ((unsigned int)f2bf(y) << 16);
}

// scalar W[d][n] over concatenated heads
static __device__ __forceinline__ float wsrc(const float* wc, const float* wb,
                                             const float* wm, int d, int n) {
    if (n < NCH)        return wc[d * NCH + n];
    if (n < NCH + NBE)  return wb[d * NBE + (n - NCH)];
    if (n < NOUT)       return wm[(long)d * NME + (n - NCH - NBE)];
    return 0.f;
}
// quad W[d][n0..n0+3]; head boundaries (24,40,168) are 4-aligned so quads never straddle
static __device__ __forceinline__ f32x4 wsrc4(const float* wc, const float* wb,
                                              const float* wm, int d, int nq) {
    int n0 = nq * 4;
    if (n0 < 24)  return *(const f32x4*)(wc + d * 24 + n0);
    if (n0 < 40)  return *(const f32x4*)(wb + d * 16 + (n0 - 24));
    if (n0 < 168) return *(const f32x4*)(wm + (long)d * 128 + (n0 - 40));
    f32x4 z = {0.f, 0.f, 0.f, 0.f};
    return z;
}

// folded, transposed, bf16 weights: wbt[n][r], r = d-256
__global__ __launch_bounds__(256) void k_fold(const float* wc, const float* wb,
                                              const float* wm_, const float* conv_w,
                                              unsigned short* wbt) {
    __shared__ unsigned short tile[64 * 196];   // [dloc][n], pad 196 (8B-aligned rows)
    float cw0 = conv_w[3], cw1 = conv_w[4], cw2 = conv_w[5];
    int r0 = blockIdx.x * 64;
    int tid = threadIdx.x;
    for (int i = 0; i < 12; ++i) {
        int idx = tid + i * 256;                // 64 rows x 48 quads
        int dl = idx / 48, nq = idx % 48;
        int r = r0 + dl;
        f32x4 v = {0.f, 0.f, 0.f, 0.f};
        if (r < 50681) {                        // rows >= 50681 stay zero (pads A-tail)
            int d = 256 + r;
            f32x4 w0 = wsrc4(wc, wb, wm_, d, nq);
            f32x4 wn1 = wsrc4(wc, wb, wm_, d - 1, nq);
            v = cw1 * w0 + cw2 * wn1;
            if (d + 1 < D_IN_) v += cw0 * wsrc4(wc, wb, wm_, d + 1, nq);
        }
        u32x2 p; p.x = pack2(v.x, v.y); p.y = pack2(v.z, v.w);
        *(u32x2*)&tile[dl * 196 + nq * 4] = p;
    }
    __syncthreads();
    for (int i = 0; i < 6; ++i) {
        int idx = tid + i * 256;                // 192 n x 8 chunks
        int n = idx >> 3, ch = idx & 7;
        short8 o;
        for (int j = 0; j < 8; ++j) o[j] = (short)tile[(ch * 8 + j) * 196 + n];
        *(short8*)(wbt + (long)n * KROWS + r0 + ch * 8) = o;
    }
}

// C[j] = bias + ctx @ W'[0:256, j] (+ conv_b * colsum, generally zero); ctx fused in
__global__ void k_cvec(const int* genre, const int* tempo, const int* keysig,
                       const float* emb,
                       const float* wc, const float* wb, const float* wm_,
                       const float* conv_w, const float* conv_b,
                       const float* bc, const float* bb, const float* bm_, float* C) {
    int j = blockIdx.x;          // 0..167
    int lane = threadIdx.x;      // 64
    int g = genre[0], tt = tempo[0], kk = keysig[0];
    float cw0 = conv_w[3], cw1 = conv_w[4], cw2 = conv_w[5];
    float s = 0.f;
    for (int d = lane; d < 256; d += 64) {
        float cx = emb[g * 256 + d] + emb[(10 + tt) * 256 + d] +
                   emb[(20 + kk) * 256 + d] + emb[34 * 256 + d];
        float wp = cw1 * wsrc(wc, wb, wm_, d, j) + cw0 * wsrc(wc, wb, wm_, d + 1, j);
        if (d > 0) wp += cw2 * wsrc(wc, wb, wm_, d - 1, j);
        s += cx * wp;
    }
    float cb = conv_b[0];
    if (cb != 0.f) {
        float cs = 0.f;
        for (int d = lane; d < D_IN_; d += 64) cs += wsrc(wc, wb, wm_, d, j);
        s += cb * cs;
    }
    for (int off = 32; off; off >>= 1) s += __shfl_down(s, off);
    if (lane == 0) {
        float b = (j < NCH) ? bc[j] : (j < NCH + NBE) ? bb[j - NCH] : bm_[j - NCH - NBE];
        C[j] = s + b;
    }
}

// Split-K GEMM, 2-deep counted-vmcnt pipeline (T3+T4), modulo-3 correct:
//  - 3 LDS buffers for B, 3 named A-regsets (phase t: compute buf/reg t%3,
//    prefetch t+2 into buf/reg (t+2)%3 = (t-1)%3, whose reads retired before
//    the phase-(t-1) barrier).
//  - vmcnt(11) per barrier = loadA(t+1)[>=4] + glds(t+2)[3] + loadA(t+2)[>=4]
//    newer ops: retires exactly glds(t+1); A-loads stay in flight ~2 phases.
//    Counting is conservative-safe if f32x4 loads split (count only grows).
//  - 512 thr = 8 waves = 4 M x 2 N; tile 64x192; 72 KB LDS -> 2 blocks/CU.
__global__ __launch_bounds__(512, 4) void k_gemm(const float* mel, const float* lyr,
                                                 const unsigned short* wbt,
                                                 float* partial) {
    __shared__ unsigned short Bs[3 * NPAD * 64];   // 3 x 24 KB
    const int blk = blockIdx.x;
    const int ks = ((blk & 7) << 1) | ((blk >> 3) & 1);  // XCD x -> ks {2x,2x+1}
    const int bm = blk >> 4;                             // 0..31 (64-row tiles)
    const int tid = threadIdx.x, lane = tid & 63, wv = tid >> 6;
    const int wm = wv >> 1, wn = wv & 1;
    const int l15 = lane & 15, lk = lane >> 4;
    const int start = ks * 49 + (ks < 8 ? ks : 8);
    const int cnt = 49 + (ks < 8 ? 1 : 0);

    const int arow = bm * 64 + wm * 16 + l15;
    const float* melB = mel + arow * 256;
    const float* lyrB = lyr + (long)arow * D_LYR_ - 256;   // +r gives lyric col

    const int bnl = lane >> 3, bcs = lane & 7;     // B-stage lane coords

    f32x4 acc[6];
    #pragma unroll
    for (int i = 0; i < 6; ++i) acc[i] = (f32x4){0.f, 0.f, 0.f, 0.f};

    auto stageB = [&](int t, int buf) {            // 3 glds / wave, 24 KB / block
        int r0 = (start + t) * 64;
        #pragma unroll
        for (int j = 0; j < 3; ++j) {
            int n0 = wv * 24 + j * 8;
            int n = n0 + bnl;
            const unsigned short* gp =
                wbt + (long)n * KROWS + r0 + ((bcs ^ (n & 7)) * 8);  // inverse swizzle
            __builtin_amdgcn_global_load_lds((glob_u32*)gp,
                                             (lds_u32*)(Bs + buf * (NPAD * 64) + n0 * 64),
                                             16, 0, 0);
        }
    };

    auto loadA = [&](int t, f32x4* dst) {          // dst[4] = [kk*2 + half]
        int gt = start + t;
        int r0 = gt * 64;
        if (gt != TOTSTEP - 1) {                   // uniform fast path: 4 vec loads
            #pragma unroll
            for (int kk = 0; kk < 2; ++kk) {
                int r = r0 + kk * 32 + lk * 8;
                const float* p = (r < 256) ? (melB + r) : (lyrB + r);
                dst[kk * 2]     = *(const f32x4u*)p;
                dst[kk * 2 + 1] = *(const f32x4u*)(p + 4);
            }
        } else {                                   // tail tile (block-uniform branch):
            #pragma unroll                         // per-element guard, never OOB;
            for (int kk = 0; kk < 2; ++kk) {       // garbage k>=D_LYR_ hits zero weights
                int r = r0 + kk * 32 + lk * 8;
                const float* p = lyrB + r;
                int c = r - 256;
                f32x4 v0, v1;
                #pragma unroll
                for (int q = 0; q < 4; ++q) {
                    v0[q] = (c + q     < D_LYR_) ? p[q]     : 0.f;
                    v1[q] = (c + 4 + q < D_LYR_) ? p[4 + q] : 0.f;
                }
                dst[kk * 2] = v0; dst[kk * 2 + 1] = v1;
            }
        }
    };

    auto compute = [&](const f32x4* a, int buf) {
        const unsigned short* Bb = Bs + buf * (NPAD * 64);
        #pragma unroll
        for (int kk = 0; kk < 2; ++kk) {
            f32x4 v0 = a[kk * 2], v1 = a[kk * 2 + 1];
            short8 af;
            af[0] = (short)f2bf(v0.x); af[1] = (short)f2bf(v0.y);
            af[2] = (short)f2bf(v0.z); af[3] = (short)f2bf(v0.w);
            af[4] = (short)f2bf(v1.x); af[5] = (short)f2bf(v1.y);
            af[6] = (short)f2bf(v1.z); af[7] = (short)f2bf(v1.w);
            #pragma unroll
            for (int ni = 0; ni < 6; ++ni) {
                int n = wn * 96 + ni * 16 + l15;
                int slot = (kk * 4 + lk) ^ (n & 7);
                short8 bf = *(const short8*)(Bb + n * 64 + slot * 8);
                acc[ni] = __builtin_amdgcn_mfma_f32_16x16x32_bf16(af, bf, acc[ni], 0, 0, 0);
            }
        }
    };

    f32x4 rg0[4], rg1[4], rg2[4];
    // prologue: tiles 0,1 staged; wait retires glds(0) only (11 newer ops remain)
    stageB(0, 0); loadA(0, rg0);
    stageB(1, 1); loadA(1, rg1);
    asm volatile("s_waitcnt vmcnt(11)" ::: "memory");
    __builtin_amdgcn_sched_barrier(0);
    __builtin_amdgcn_s_barrier();
    __builtin_amdgcn_sched_barrier(0);

#define PHASE(CUR, NXT, RGCUR, RGNXT)                                   \
    {                                                                   \
        bool pf = (t + 2 < cnt);                                        \
        if (pf) { stageB(t + 2, NXT); loadA(t + 2, RGNXT); }            \
        __builtin_amdgcn_sched_barrier(0);                              \
        compute(RGCUR, CUR);                                            \
        if (t + 1 >= cnt) break;                                        \
        if (pf) { asm volatile("s_waitcnt vmcnt(11)" ::: "memory"); }   \
        else    { asm volatile("s_waitcnt vmcnt(4)"  ::: "memory"); }   \
        __builtin_amdgcn_sched_barrier(0);                              \
        __builtin_amdgcn_s_barrier();                                   \
        __builtin_amdgcn_sched_barrier(0);                              \
        ++t;                                                            \
    }

    int t = 0;
    while (true) {
        PHASE(0, 2, rg0, rg2)
        PHASE(1, 0, rg1, rg0)
        PHASE(2, 1, rg2, rg1)
    }
#undef PHASE

    // deterministic partial store
    float* pbase = partial + (long)ks * PARTN;
    int rb = bm * 64 + wm * 16 + lk * 4;
    #pragma unroll
    for (int ni = 0; ni < 6; ++ni) {
        int col = wn * 96 + ni * 16 + l15;
        if (col < NOUT) {
            #pragma unroll
            for (int q = 0; q < 4; ++q)
                pbase[(long)(rb + q) * NOUT + col] = acc[ni][q];
        }
    }
}

__global__ void k_reduce(const float* partial, const float* C, float* out) {
    int idx = blockIdx.x * 256 + threadIdx.x;    // vec4 index
    if (idx >= PARTN / 4) return;
    int base = idx * 4;
    f32x4 s;
    for (int q = 0; q < 4; ++q) s[q] = C[(base + q) % NOUT];
    for (int ks = 0; ks < KSPLIT; ++ks)
        s += *(const f32x4*)(partial + (long)ks * PARTN + base);
    *(f32x4*)(out + base) = s;
}

extern "C" void kernel_launch(void* const* d_in, const int* in_sizes, int n_in,
                              void* d_out, int out_size, void* d_ws, size_t ws_size,
                              hipStream_t stream) {
    const int*   genre   = (const int*)d_in[0];
    const int*   tempo   = (const int*)d_in[1];
    const int*   keysig  = (const int*)d_in[2];
    const float* mel     = (const float*)d_in[4];
    const float* lyr     = (const float*)d_in[5];
    const float* emb     = (const float*)d_in[6];
    const float* conv_w  = (const float*)d_in[7];
    const float* conv_b  = (const float*)d_in[8];
    const float* w_chord = (const float*)d_in[9];
    const float* b_chord = (const float*)d_in[10];
    const float* w_beat  = (const float*)d_in[11];
    const float* b_beat  = (const float*)d_in[12];
    const float* w_mel   = (const float*)d_in[13];
    const float* b_mel   = (const float*)d_in[14];

    char* ws = (char*)d_ws;
    unsigned short* wbt = (unsigned short*)ws;              // 192*50688*2 = 19,464,192 B
    float* Cvec    = (float*)(ws + 19464192);               // 1 KB
    float* partial = (float*)(ws + 19466240);               // 16*344064*4 = 22,020,096 B
    float* out     = (float*)d_out;

    hipLaunchKernelGGL(k_fold, dim3(TOTSTEP), dim3(256), 0, stream,
                       w_chord, w_beat, w_mel, conv_w, wbt);
    hipLaunchKernelGGL(k_cvec, dim3(NOUT), dim3(64), 0, stream,
                       genre, tempo, keysig, emb,
                       w_chord, w_beat, w_mel, conv_w, conv_b,
                       b_chord, b_beat, b_mel, Cvec);
    hipLaunchKernelGGL(k_gemm, dim3(512), dim3(512), 0, stream,
                       mel, lyr, wbt, partial);
    hipLaunchKernelGGL(k_reduce, dim3((PARTN / 4 + 255) / 256), dim3(256), 0, stream,
                       partial, Cvec, out);
}